// Round 9
// baseline (14206.804 us; speedup 1.0000x reference)
//
#include <hip/hip_runtime.h>
#include <cmath>

#define TT   2048
#define EE   300
#define HH   512
#define G4H  2048     // 4*H
#define NTAG 25
#define NEGV (-10000.0f)
#define POISON 0xFFBADBADu   // NaN payload; published W*h values can never be NaN

typedef uint32_t u32x4 __attribute__((ext_vector_type(4)));

__device__ __forceinline__ float fsig(float x)  { return 1.f / (1.f + __expf(-x)); }
__device__ __forceinline__ float ftanh(float x) { return 1.f - 2.f / (__expf(2.f * x) + 1.f); }
__device__ __forceinline__ uint32_t f2u(float x) { return __float_as_uint(x); }
__device__ __forceinline__ float u2f(uint32_t x) { return __uint_as_float(x); }

// 16B load bypassing L1+L2 (coherent at L3 across XCDs), fused waitcnt:
// output defined only after the internal wait -> no cross-region reg hazard.
__device__ __forceinline__ u32x4 poll16(const uint32_t* p) {
    u32x4 v;
    asm volatile("global_load_dwordx4 %0, %1, off sc0 sc1\n\t"
                 "s_waitcnt vmcnt(0)"
                 : "=v"(v) : "v"(p) : "memory");
    return v;
}
// 16B write-through store (single full-quad transaction, no partial lines)
__device__ __forceinline__ void store16(uint32_t* p, u32x4 v) {
    asm volatile("global_store_dwordx4 %0, %1, off sc0 sc1"
                 :: "v"(p), "v"(v) : "memory");
}

// ---------------- poison gates buffer (data-as-sync sentinel) ----------------
__global__ void poison_kernel(uint32_t* __restrict__ p, int n) {
    int i = blockIdx.x * blockDim.x + threadIdx.x;
    for (; i < n; i += gridDim.x * blockDim.x) p[i] = POISON;
}

// ---------------- embedding gather ----------------
__global__ void embed_kernel(const int* __restrict__ sent,
                             const float* __restrict__ emb,
                             float* __restrict__ x) {
    int t = blockIdx.x;
    int row = sent[t];
    const float4* src = (const float4*)(emb + (size_t)row * EE);
    float4* dst = (float4*)(x + (size_t)t * EE);
    for (int i = threadIdx.x; i < EE / 4; i += blockDim.x) dst[i] = src[i];
}

// ---------------- GEMM (generic, bounds-checked): C = A*B^T + b1 (+ b2) ------
#define BM 64
#define BN 64
#define BKK 16
__global__ __launch_bounds__(256)
void gemm_abt(const float* __restrict__ A, int lda,
              const float* __restrict__ B, int ldb,
              const float* __restrict__ bias1,
              const float* __restrict__ bias2,
              float* __restrict__ C, int ldc,
              int M, int N, int K) {
    __shared__ float As[BKK][BM + 4];
    __shared__ float Bs[BKK][BN + 4];
    const int tid = threadIdx.x;
    const int tx = tid & 15, ty = tid >> 4;
    const int bm = blockIdx.x * BM, bn = blockIdx.y * BN;
    float acc[4][4] = {};
    for (int k0 = 0; k0 < K; k0 += BKK) {
        #pragma unroll
        for (int i = 0; i < 4; ++i) {
            int m = (tid >> 4) + i * 16;
            int k = tid & 15;
            float a = 0.f, b = 0.f;
            if (k0 + k < K) {
                if (bm + m < M) a = A[(size_t)(bm + m) * lda + k0 + k];
                if (bn + m < N) b = B[(size_t)(bn + m) * ldb + k0 + k];
            }
            As[k][m] = a;
            Bs[k][m] = b;
        }
        __syncthreads();
        #pragma unroll
        for (int k = 0; k < BKK; ++k) {
            float4 a4 = *(const float4*)&As[k][ty * 4];
            float4 b4 = *(const float4*)&Bs[k][tx * 4];
            acc[0][0] += a4.x * b4.x; acc[0][1] += a4.x * b4.y;
            acc[0][2] += a4.x * b4.z; acc[0][3] += a4.x * b4.w;
            acc[1][0] += a4.y * b4.x; acc[1][1] += a4.y * b4.y;
            acc[1][2] += a4.y * b4.z; acc[1][3] += a4.y * b4.w;
            acc[2][0] += a4.z * b4.x; acc[2][1] += a4.z * b4.y;
            acc[2][2] += a4.z * b4.z; acc[2][3] += a4.z * b4.w;
            acc[3][0] += a4.w * b4.x; acc[3][1] += a4.w * b4.y;
            acc[3][2] += a4.w * b4.z; acc[3][3] += a4.w * b4.w;
        }
        __syncthreads();
    }
    #pragma unroll
    for (int i = 0; i < 4; ++i) {
        int m = bm + ty * 4 + i;
        if (m < M) {
            #pragma unroll
            for (int j = 0; j < 4; ++j) {
                int n = bn + tx * 4 + j;
                if (n < N) {
                    float v = acc[i][j];
                    if (bias1) v += bias1[n];
                    if (bias2) v += bias2[n];
                    C[(size_t)m * ldc + n] = v;
                }
            }
        }
    }
}

// ---------------- big GEMM (128x128 tile, 8x8/thread) ----------------
#define GM 128
#define GN 128
#define GK 16
__global__ __launch_bounds__(256)
void gemm128(const float* __restrict__ A, int lda,
             const float* __restrict__ B, int ldb,
             const float* __restrict__ bias1,
             const float* __restrict__ bias2,
             float* __restrict__ C, int ldc, int K) {
    __shared__ float As[GK][GM + 4];
    __shared__ float Bs[GK][GN + 4];
    const int tid = threadIdx.x;
    const int tx = tid & 15, ty = tid >> 4;
    const int bm = blockIdx.x * GM, bn = blockIdx.y * GN;
    const int lm = tid >> 1, lkq = (tid & 1) * 8;
    float acc[8][8] = {};
    for (int k0 = 0; k0 < K; k0 += GK) {
        float4 a0 = *(const float4*)&A[(size_t)(bm + lm) * lda + k0 + lkq];
        float4 a1 = *(const float4*)&A[(size_t)(bm + lm) * lda + k0 + lkq + 4];
        float4 b0 = *(const float4*)&B[(size_t)(bn + lm) * ldb + k0 + lkq];
        float4 b1 = *(const float4*)&B[(size_t)(bn + lm) * ldb + k0 + lkq + 4];
        As[lkq + 0][lm] = a0.x; As[lkq + 1][lm] = a0.y;
        As[lkq + 2][lm] = a0.z; As[lkq + 3][lm] = a0.w;
        As[lkq + 4][lm] = a1.x; As[lkq + 5][lm] = a1.y;
        As[lkq + 6][lm] = a1.z; As[lkq + 7][lm] = a1.w;
        Bs[lkq + 0][lm] = b0.x; Bs[lkq + 1][lm] = b0.y;
        Bs[lkq + 2][lm] = b0.z; Bs[lkq + 3][lm] = b0.w;
        Bs[lkq + 4][lm] = b1.x; Bs[lkq + 5][lm] = b1.y;
        Bs[lkq + 6][lm] = b1.z; Bs[lkq + 7][lm] = b1.w;
        __syncthreads();
        #pragma unroll
        for (int k = 0; k < GK; ++k) {
            float4 x0 = *(const float4*)&As[k][ty * 8];
            float4 x1 = *(const float4*)&As[k][ty * 8 + 4];
            float4 y0 = *(const float4*)&Bs[k][tx * 8];
            float4 y1 = *(const float4*)&Bs[k][tx * 8 + 4];
            float xa[8] = {x0.x, x0.y, x0.z, x0.w, x1.x, x1.y, x1.z, x1.w};
            float yb[8] = {y0.x, y0.y, y0.z, y0.w, y1.x, y1.y, y1.z, y1.w};
            #pragma unroll
            for (int i = 0; i < 8; ++i)
                #pragma unroll
                for (int j = 0; j < 8; ++j)
                    acc[i][j] += xa[i] * yb[j];
        }
        __syncthreads();
    }
    #pragma unroll
    for (int i = 0; i < 8; ++i) {
        int m = bm + ty * 8 + i;
        float* cr = C + (size_t)m * ldc + bn + tx * 8;
        #pragma unroll
        for (int j = 0; j < 8; ++j) {
            float v = acc[i][j];
            int n = bn + tx * 8 + j;
            if (bias1) v += bias1[n];
            if (bias2) v += bias2[n];
            cr[j] = v;
        }
    }
}

// -------- persistent dual-direction BiLSTM (unit-quad publish, consumer gx) ---
// 32 WGs x 512 threads, launch_bounds(512,1) (r4 lesson: (512,2) caps VGPR at
// 128 -> weight spill). 32-lane group g owns unit u=wg*16+g for BOTH dirs:
// rows {u, 512+u, 1024+u, 1536+u}, lane l covers h floats {4(l+32i)..+3}.
// Producers publish RAW W*h as ONE dwordx4 (full 16B quad, single store -> no
// partial-line false sharing, r5 lesson). Consumers add gx at activation
// (prefetched 1 step ahead). fwd poll RT hides under bwd dot and vice versa.
// Every WG redundantly tracks c[tid] for all 512 units of both dirs.
__global__ __launch_bounds__(512, 1)
void lstm_kernel(const float* __restrict__ gx,      // [2][T][4H] input proj + biases
                 const float* __restrict__ whh_f,   // [4H][H]
                 const float* __restrict__ whh_b,   // [4H][H]
                 float* __restrict__ gates,         // [2][T][512][4] packed, poisoned
                 float* __restrict__ hout)          // [T][2H]
{
    const int tid = threadIdx.x;
    const int wg  = blockIdx.x;          // 0..31
    const int g   = tid >> 5;            // unit group 0..15
    const int l   = tid & 31;            // reduction lane
    const int u   = wg * 16 + g;         // produced unit (both dirs)

    // weights: 4 gate rows x 16 floats per dir = 16 float4 per dir
    float4 wf[16], wb[16];
    #pragma unroll
    for (int gb = 0; gb < 4; ++gb) {
        const float4* rf = (const float4*)(whh_f + (size_t)(gb * HH + u) * HH);
        const float4* rb = (const float4*)(whh_b + (size_t)(gb * HH + u) * HH);
        #pragma unroll
        for (int i = 0; i < 4; ++i) {
            wf[gb * 4 + i] = rf[l + 32 * i];
            wb[gb * 4 + i] = rb[l + 32 * i];
        }
    }
    #pragma unroll
    for (int i = 0; i < 16; ++i) {
        asm volatile("" : "+v"(wf[i].x), "+v"(wf[i].y), "+v"(wf[i].z), "+v"(wf[i].w));
        asm volatile("" : "+v"(wb[i].x), "+v"(wb[i].y), "+v"(wb[i].z), "+v"(wb[i].w));
    }

    __shared__ float hf_s[HH];
    __shared__ float hb_s[HH];

    float cf = 0.f, cb = 0.f;            // replicated cell state of unit `tid`
    uint32_t* gqf = (uint32_t*)gates;                       // [T][512][4]
    uint32_t* gqb = (uint32_t*)gates + (size_t)TT * G4H;
    const float* gxf = gx;
    const float* gxb = gx + (size_t)TT * G4H;

    // consumer gx quads (i,f,g,o of unit tid), prefetched 1 step ahead
    float4 xfC{}, xbC{}, xfN{}, xbN{};

    for (int s = 0; s <= TT; ++s) {
        // ================= forward: consume gates(s-1) =================
        float hfv;
        if (s > 0) {
            const uint32_t* p = gqf + ((size_t)(s - 1) * HH + tid) * 4;
            u32x4 v;
            do { v = poll16(p); }
            while ((v.x == POISON) | (v.y == POISON) |
                   (v.z == POISON) | (v.w == POISON));
            float gi = fsig (u2f(v.x) + xfC.x);
            float gf = fsig (u2f(v.y) + xfC.y);
            float gg = ftanh(u2f(v.z) + xfC.z);
            float go = fsig (u2f(v.w) + xfC.w);
            cf = gf * cf + gi * gg;
            hfv = go * ftanh(cf);
            if (wg == 0) hout[(size_t)(s - 1) * (2 * HH) + tid] = hfv;
        } else {
            hfv = 0.f;
        }
        hf_s[tid] = hfv;
        // prefetch fwd gx for step s (consumed at iter s+1)
        if (s < TT) {
            const float* q = gxf + (size_t)s * G4H + tid;
            xfN = make_float4(q[0], q[HH], q[2 * HH], q[3 * HH]);
        }
        __syncthreads();                               // B1: hf ready

        if (s < TT) {
            float a0 = 0.f, a1 = 0.f, a2 = 0.f, a3 = 0.f;
            const float4* h4 = (const float4*)hf_s;
            #pragma unroll
            for (int i = 0; i < 4; ++i) {
                float4 hv = h4[l + 32 * i];
                a0 += wf[0  + i].x * hv.x + wf[0  + i].y * hv.y + wf[0  + i].z * hv.z + wf[0  + i].w * hv.w;
                a1 += wf[4  + i].x * hv.x + wf[4  + i].y * hv.y + wf[4  + i].z * hv.z + wf[4  + i].w * hv.w;
                a2 += wf[8  + i].x * hv.x + wf[8  + i].y * hv.y + wf[8  + i].z * hv.z + wf[8  + i].w * hv.w;
                a3 += wf[12 + i].x * hv.x + wf[12 + i].y * hv.y + wf[12 + i].z * hv.z + wf[12 + i].w * hv.w;
            }
            #pragma unroll
            for (int m = 1; m <= 16; m <<= 1) {
                a0 += __shfl_xor(a0, m); a1 += __shfl_xor(a1, m);
                a2 += __shfl_xor(a2, m); a3 += __shfl_xor(a3, m);
            }
            if (l == 0) {
                u32x4 q; q.x = f2u(a0); q.y = f2u(a1); q.z = f2u(a2); q.w = f2u(a3);
                store16(gqf + ((size_t)s * HH + u) * 4, q);
            }
        }

        // ================= backward: consume gates(s-1) =================
        float hbv;
        if (s > 0) {
            const uint32_t* p = gqb + ((size_t)(s - 1) * HH + tid) * 4;
            u32x4 v;
            do { v = poll16(p); }
            while ((v.x == POISON) | (v.y == POISON) |
                   (v.z == POISON) | (v.w == POISON));
            float gi = fsig (u2f(v.x) + xbC.x);
            float gf = fsig (u2f(v.y) + xbC.y);
            float gg = ftanh(u2f(v.z) + xbC.z);
            float go = fsig (u2f(v.w) + xbC.w);
            cb = gf * cb + gi * gg;
            hbv = go * ftanh(cb);
            if (wg == 0) hout[(size_t)(TT - s) * (2 * HH) + HH + tid] = hbv;
        } else {
            hbv = 0.f;
        }
        hb_s[tid] = hbv;
        // prefetch bwd gx for time TT-1-s (consumed at iter s+1)
        if (s < TT) {
            const float* q = gxb + (size_t)(TT - 1 - s) * G4H + tid;
            xbN = make_float4(q[0], q[HH], q[2 * HH], q[3 * HH]);
        }
        __syncthreads();                               // B2: hb ready

        if (s < TT) {
            float a0 = 0.f, a1 = 0.f, a2 = 0.f, a3 = 0.f;
            const float4* h4 = (const float4*)hb_s;
            #pragma unroll
            for (int i = 0; i < 4; ++i) {
                float4 hv = h4[l + 32 * i];
                a0 += wb[0  + i].x * hv.x + wb[0  + i].y * hv.y + wb[0  + i].z * hv.z + wb[0  + i].w * hv.w;
                a1 += wb[4  + i].x * hv.x + wb[4  + i].y * hv.y + wb[4  + i].z * hv.z + wb[4  + i].w * hv.w;
                a2 += wb[8  + i].x * hv.x + wb[8  + i].y * hv.y + wb[8  + i].z * hv.z + wb[8  + i].w * hv.w;
                a3 += wb[12 + i].x * hv.x + wb[12 + i].y * hv.y + wb[12 + i].z * hv.z + wb[12 + i].w * hv.w;
            }
            #pragma unroll
            for (int m = 1; m <= 16; m <<= 1) {
                a0 += __shfl_xor(a0, m); a1 += __shfl_xor(a1, m);
                a2 += __shfl_xor(a2, m); a3 += __shfl_xor(a3, m);
            }
            if (l == 0) {
                u32x4 q; q.x = f2u(a0); q.y = f2u(a1); q.z = f2u(a2); q.w = f2u(a3);
                store16(gqb + ((size_t)s * HH + u) * 4, q);
            }
        }

        xfC = xfN; xbC = xbN;
    }
}

// ---------------- Viterbi forward + backtrack (bp in LDS as bytes) -----------
__global__ void viterbi_kernel(const float* __restrict__ feats,
                               const float* __restrict__ trans,
                               int* __restrict__ out) {
    const int n = threadIdx.x;   // blockDim = 64 (one wave)
    __shared__ float fv_s[NTAG];
    __shared__ uint8_t bp_s[TT][NTAG];   // 51200 B
    float tr[NTAG];
    if (n < NTAG) {
        #pragma unroll
        for (int p = 0; p < NTAG; ++p) tr[p] = trans[n * NTAG + p];
    }
    float fv = (n == 0) ? 0.f : NEGV;
    for (int t = 0; t < TT; ++t) {
        if (n < NTAG) fv_s[n] = fv;
        __syncthreads();
        if (n < NTAG) {
            float best = -INFINITY; int bb = 0;
            #pragma unroll
            for (int p = 0; p < NTAG; ++p) {
                float sc = fv_s[p] + tr[p];
                if (sc > best) { best = sc; bb = p; }   // first-max tie rule
            }
            bp_s[t][n] = (uint8_t)bb;
            fv = best + feats[t * NTAG + n];
        }
        __syncthreads();
    }
    if (n < NTAG) fv_s[n] = fv;
    __syncthreads();
    if (n == 0) {
        float best = -INFINITY; int tag = 0;
        for (int p = 0; p < NTAG; ++p)
            if (fv_s[p] > best) { best = fv_s[p]; tag = p; }
        for (int t = TT - 1; t >= 0; --t) {
            out[t] = tag;
            tag = bp_s[t][tag];
        }
    }
}

extern "C" void kernel_launch(void* const* d_in, const int* in_sizes, int n_in,
                              void* d_out, int out_size, void* d_ws, size_t ws_size,
                              hipStream_t stream) {
    const int*   sent      = (const int*)d_in[0];
    const float* emb       = (const float*)d_in[1];
    const float* w_ih_l0_f = (const float*)d_in[2];
    const float* w_hh_l0_f = (const float*)d_in[3];
    const float* b_ih_l0_f = (const float*)d_in[4];
    const float* b_hh_l0_f = (const float*)d_in[5];
    const float* w_ih_l0_b = (const float*)d_in[6];
    const float* w_hh_l0_b = (const float*)d_in[7];
    const float* b_ih_l0_b = (const float*)d_in[8];
    const float* b_hh_l0_b = (const float*)d_in[9];
    const float* w_ih_l1_f = (const float*)d_in[10];
    const float* w_hh_l1_f = (const float*)d_in[11];
    const float* b_ih_l1_f = (const float*)d_in[12];
    const float* b_hh_l1_f = (const float*)d_in[13];
    const float* w_ih_l1_b = (const float*)d_in[14];
    const float* w_hh_l1_b = (const float*)d_in[15];
    const float* b_ih_l1_b = (const float*)d_in[16];
    const float* b_hh_l1_b = (const float*)d_in[17];
    const float* w_tag     = (const float*)d_in[18];
    const float* b_tag     = (const float*)d_in[19];
    const float* trans     = (const float*)d_in[20];

    char* ws = (char*)d_ws;
    float* x     = (float*)(ws);                 // T*300   = 2,457,600 B
    float* gx    = (float*)(ws + 2457600);       // 2*T*4H  = 33,554,432 B
    float* gates = (float*)(ws + 36012032);      // 2*T*4H  = 33,554,432 B ([2][T][512][4])
    float* h1    = (float*)(ws + 69566464);      // T*2H    = 8,388,608 B
    float* h2    = (float*)(ws + 77955072);      // T*2H    = 8,388,608 B
    float* feats = (float*)(ws + 86343680);      // T*25

    const int NGATES = 2 * TT * G4H;

    poison_kernel<<<2048, 256, 0, stream>>>((uint32_t*)gates, NGATES);

    embed_kernel<<<TT, 128, 0, stream>>>(sent, emb, x);

    dim3 g0(TT / BM, G4H / BN);
    gemm_abt<<<g0, 256, 0, stream>>>(x, EE, w_ih_l0_f, EE, b_ih_l0_f, b_hh_l0_f,
                                     gx, G4H, TT, G4H, EE);
    gemm_abt<<<g0, 256, 0, stream>>>(x, EE, w_ih_l0_b, EE, b_ih_l0_b, b_hh_l0_b,
                                     gx + (size_t)TT * G4H, G4H, TT, G4H, EE);
    lstm_kernel<<<32, 512, 0, stream>>>(gx, w_hh_l0_f, w_hh_l0_b, gates, h1);

    dim3 g1(TT / GM, G4H / GN);
    gemm128<<<g1, 256, 0, stream>>>(h1, 2 * HH, w_ih_l1_f, 2 * HH, b_ih_l1_f, b_hh_l1_f,
                                    gx, G4H, 2 * HH);
    gemm128<<<g1, 256, 0, stream>>>(h1, 2 * HH, w_ih_l1_b, 2 * HH, b_ih_l1_b, b_hh_l1_b,
                                    gx + (size_t)TT * G4H, G4H, 2 * HH);
    poison_kernel<<<2048, 256, 0, stream>>>((uint32_t*)gates, NGATES);
    lstm_kernel<<<32, 512, 0, stream>>>(gx, w_hh_l1_f, w_hh_l1_b, gates, h2);

    dim3 gf(TT / BM, 1);
    gemm_abt<<<gf, 256, 0, stream>>>(h2, 2 * HH, w_tag, 2 * HH, b_tag, nullptr,
                                     feats, NTAG, TT, NTAG, 2 * HH);

    viterbi_kernel<<<1, 64, 0, stream>>>(feats, trans, (int*)d_out);
}

// Round 11
// 9970.377 us; speedup vs baseline: 1.4249x; 1.4249x over previous
//
#include <hip/hip_runtime.h>
#include <cmath>

#define TT   2048
#define EE   300
#define HH   512
#define G4H  2048     // 4*H
#define NTAG 25
#define NEGV (-10000.0f)
#define POISON 0xFFBADBADu   // NaN payload; published W*h values can never be NaN

typedef uint32_t u32x4 __attribute__((ext_vector_type(4)));

__device__ __forceinline__ float fsig(float x)  { return 1.f / (1.f + __expf(-x)); }
__device__ __forceinline__ float ftanh(float x) { return 1.f - 2.f / (__expf(2.f * x) + 1.f); }
__device__ __forceinline__ uint32_t f2u(float x) { return __float_as_uint(x); }
__device__ __forceinline__ float u2f(uint32_t x) { return __uint_as_float(x); }

// 16B load bypassing L1+L2 (coherent at L3 across XCDs), waitcnt INSIDE the
// asm (r10 lesson: deferring the waitcnt outside the asm breaks the compiler's
// own vmcnt bookkeeping -> memory fault).
__device__ __forceinline__ u32x4 poll16(const uint32_t* p) {
    u32x4 v;
    asm volatile("global_load_dwordx4 %0, %1, off sc0 sc1\n\t"
                 "s_waitcnt vmcnt(0)"
                 : "=v"(v) : "v"(p) : "memory");
    return v;
}
// 16B write-through store (single full-quad transaction, no partial lines)
__device__ __forceinline__ void store16(uint32_t* p, u32x4 v) {
    asm volatile("global_store_dwordx4 %0, %1, off sc0 sc1"
                 :: "v"(p), "v"(v) : "memory");
}

// ---------------- poison gates buffer (data-as-sync sentinel) ----------------
__global__ void poison_kernel(uint32_t* __restrict__ p, int n) {
    int i = blockIdx.x * blockDim.x + threadIdx.x;
    for (; i < n; i += gridDim.x * blockDim.x) p[i] = POISON;
}

// ---------------- embedding gather ----------------
__global__ void embed_kernel(const int* __restrict__ sent,
                             const float* __restrict__ emb,
                             float* __restrict__ x) {
    int t = blockIdx.x;
    int row = sent[t];
    const float4* src = (const float4*)(emb + (size_t)row * EE);
    float4* dst = (float4*)(x + (size_t)t * EE);
    for (int i = threadIdx.x; i < EE / 4; i += blockDim.x) dst[i] = src[i];
}

// ---------------- GEMM (generic, bounds-checked): C = A*B^T + b1 (+ b2) ------
#define BM 64
#define BN 64
#define BKK 16
__global__ __launch_bounds__(256)
void gemm_abt(const float* __restrict__ A, int lda,
              const float* __restrict__ B, int ldb,
              const float* __restrict__ bias1,
              const float* __restrict__ bias2,
              float* __restrict__ C, int ldc,
              int M, int N, int K) {
    __shared__ float As[BKK][BM + 4];
    __shared__ float Bs[BKK][BN + 4];
    const int tid = threadIdx.x;
    const int tx = tid & 15, ty = tid >> 4;
    const int bm = blockIdx.x * BM, bn = blockIdx.y * BN;
    float acc[4][4] = {};
    for (int k0 = 0; k0 < K; k0 += BKK) {
        #pragma unroll
        for (int i = 0; i < 4; ++i) {
            int m = (tid >> 4) + i * 16;
            int k = tid & 15;
            float a = 0.f, b = 0.f;
            if (k0 + k < K) {
                if (bm + m < M) a = A[(size_t)(bm + m) * lda + k0 + k];
                if (bn + m < N) b = B[(size_t)(bn + m) * ldb + k0 + k];
            }
            As[k][m] = a;
            Bs[k][m] = b;
        }
        __syncthreads();
        #pragma unroll
        for (int k = 0; k < BKK; ++k) {
            float4 a4 = *(const float4*)&As[k][ty * 4];
            float4 b4 = *(const float4*)&Bs[k][tx * 4];
            acc[0][0] += a4.x * b4.x; acc[0][1] += a4.x * b4.y;
            acc[0][2] += a4.x * b4.z; acc[0][3] += a4.x * b4.w;
            acc[1][0] += a4.y * b4.x; acc[1][1] += a4.y * b4.y;
            acc[1][2] += a4.y * b4.z; acc[1][3] += a4.y * b4.w;
            acc[2][0] += a4.z * b4.x; acc[2][1] += a4.z * b4.y;
            acc[2][2] += a4.z * b4.z; acc[2][3] += a4.z * b4.w;
            acc[3][0] += a4.w * b4.x; acc[3][1] += a4.w * b4.y;
            acc[3][2] += a4.w * b4.z; acc[3][3] += a4.w * b4.w;
        }
        __syncthreads();
    }
    #pragma unroll
    for (int i = 0; i < 4; ++i) {
        int m = bm + ty * 4 + i;
        if (m < M) {
            #pragma unroll
            for (int j = 0; j < 4; ++j) {
                int n = bn + tx * 4 + j;
                if (n < N) {
                    float v = acc[i][j];
                    if (bias1) v += bias1[n];
                    if (bias2) v += bias2[n];
                    C[(size_t)m * ldc + n] = v;
                }
            }
        }
    }
}

// ---------------- big GEMM (128x128 tile, 8x8/thread) ----------------
#define GM 128
#define GN 128
#define GK 16
__global__ __launch_bounds__(256)
void gemm128(const float* __restrict__ A, int lda,
             const float* __restrict__ B, int ldb,
             const float* __restrict__ bias1,
             const float* __restrict__ bias2,
             float* __restrict__ C, int ldc, int K) {
    __shared__ float As[GK][GM + 4];
    __shared__ float Bs[GK][GN + 4];
    const int tid = threadIdx.x;
    const int tx = tid & 15, ty = tid >> 4;
    const int bm = blockIdx.x * GM, bn = blockIdx.y * GN;
    const int lm = tid >> 1, lkq = (tid & 1) * 8;
    float acc[8][8] = {};
    for (int k0 = 0; k0 < K; k0 += GK) {
        float4 a0 = *(const float4*)&A[(size_t)(bm + lm) * lda + k0 + lkq];
        float4 a1 = *(const float4*)&A[(size_t)(bm + lm) * lda + k0 + lkq + 4];
        float4 b0 = *(const float4*)&B[(size_t)(bn + lm) * ldb + k0 + lkq];
        float4 b1 = *(const float4*)&B[(size_t)(bn + lm) * ldb + k0 + lkq + 4];
        As[lkq + 0][lm] = a0.x; As[lkq + 1][lm] = a0.y;
        As[lkq + 2][lm] = a0.z; As[lkq + 3][lm] = a0.w;
        As[lkq + 4][lm] = a1.x; As[lkq + 5][lm] = a1.y;
        As[lkq + 6][lm] = a1.z; As[lkq + 7][lm] = a1.w;
        Bs[lkq + 0][lm] = b0.x; Bs[lkq + 1][lm] = b0.y;
        Bs[lkq + 2][lm] = b0.z; Bs[lkq + 3][lm] = b0.w;
        Bs[lkq + 4][lm] = b1.x; Bs[lkq + 5][lm] = b1.y;
        Bs[lkq + 6][lm] = b1.z; Bs[lkq + 7][lm] = b1.w;
        __syncthreads();
        #pragma unroll
        for (int k = 0; k < GK; ++k) {
            float4 x0 = *(const float4*)&As[k][ty * 8];
            float4 x1 = *(const float4*)&As[k][ty * 8 + 4];
            float4 y0 = *(const float4*)&Bs[k][tx * 8];
            float4 y1 = *(const float4*)&Bs[k][tx * 8 + 4];
            float xa[8] = {x0.x, x0.y, x0.z, x0.w, x1.x, x1.y, x1.z, x1.w};
            float yb[8] = {y0.x, y0.y, y0.z, y0.w, y1.x, y1.y, y1.z, y1.w};
            #pragma unroll
            for (int i = 0; i < 8; ++i)
                #pragma unroll
                for (int j = 0; j < 8; ++j)
                    acc[i][j] += xa[i] * yb[j];
        }
        __syncthreads();
    }
    #pragma unroll
    for (int i = 0; i < 8; ++i) {
        int m = bm + ty * 8 + i;
        float* cr = C + (size_t)m * ldc + bn + tx * 8;
        #pragma unroll
        for (int j = 0; j < 8; ++j) {
            float v = acc[i][j];
            int n = bn + tx * 8 + j;
            if (bias1) v += bias1[n];
            if (bias2) v += bias2[n];
            cr[j] = v;
        }
    }
}

// ------- persistent BiLSTM recurrence (one dir/WG, unit-quad, LOOP-PINNED w) --
// 64 WGs x 512 threads: blockIdx<32 -> fwd, >=32 -> bwd (r3 topology).
// 32-lane group g owns unit u=wg*16+g: gate rows {u,512+u,1024+u,1536+u};
// lane l covers h floats {4(l+32i)..+3}. Weights loaded with PLAIN loads, then
// re-pinned with an empty "+v" asm INSIDE the step loop: the loop-carried
// asm-modification makes remat-from-memory illegal, forcing VGPR residency
// (r3..r9 lesson: VGPR_Count 52..96 < footprint proved the pin never held;
// r10 lesson: volatile asm loads w/o internal waitcnt memory-fault).
// Producer publishes raw W*h as ONE store16 (r5: no partial-line sharing).
// Consumer polls ONE dwordx4/unit, adds gx prefetched BEFORE the poll.
// Double-buffered h_s -> ONE barrier/step (skew bounded by barrier to 1 buf).
__global__ __launch_bounds__(512, 1)
void lstm_kernel(const float* __restrict__ gx,      // [2][T][4H] input proj + biases
                 const float* __restrict__ whh_f,   // [4H][H]
                 const float* __restrict__ whh_b,   // [4H][H]
                 float* __restrict__ gates,         // [2][T][512][4] packed, poisoned
                 float* __restrict__ hout)          // [T][2H]
{
    const int tid = threadIdx.x;
    const int dir = blockIdx.x >> 5;
    const int wg  = blockIdx.x & 31;
    const int g   = tid >> 5;            // unit group 0..15
    const int l   = tid & 31;            // reduction lane
    const int u   = wg * 16 + g;         // produced unit
    const float* W = dir ? whh_b : whh_f;

    // 4 gate rows x 16 floats/lane
    float4 w[16];
    #pragma unroll
    for (int gb = 0; gb < 4; ++gb) {
        const float4* r = (const float4*)(W + (size_t)(gb * HH + u) * HH);
        #pragma unroll
        for (int i = 0; i < 4; ++i)
            w[gb * 4 + i] = r[l + 32 * i];
    }

    __shared__ float h_s[2][HH];

    float c = 0.f;                       // cell state of unit `tid` (replicated per WG)
    uint32_t* gq = (uint32_t*)gates + (size_t)dir * TT * G4H;
    const float* gxd = gx + (size_t)dir * TT * G4H;

    float4 xqC{}, xqN{};                 // gx quad of unit tid: current / next

    for (int s = 0; s <= TT; ++s) {
        // loop-carried pin: compiler must keep w in VGPRs across iterations
        #pragma unroll
        for (int i = 0; i < 16; ++i)
            asm volatile("" : "+v"(w[i].x), "+v"(w[i].y), "+v"(w[i].z), "+v"(w[i].w));

        // issue next gx prefetch FIRST: lands while we spin on the poll
        if (s < TT) {
            int tn = dir ? (TT - 1 - s) : s;
            const float* q = gxd + (size_t)tn * G4H + tid;
            xqN = make_float4(q[0], q[HH], q[2 * HH], q[3 * HH]);
        }

        float h = 0.f;
        if (s > 0) {
            const uint32_t* p = gq + ((size_t)(s - 1) * HH + tid) * 4;
            u32x4 v;
            do { v = poll16(p); }
            while ((v.x == POISON) | (v.y == POISON) |
                   (v.z == POISON) | (v.w == POISON));
            float gi = fsig (u2f(v.x) + xqC.x);
            float gf = fsig (u2f(v.y) + xqC.y);
            float gg = ftanh(u2f(v.z) + xqC.z);
            float go = fsig (u2f(v.w) + xqC.w);
            c = gf * c + gi * gg;
            h = go * ftanh(c);
            if (wg == 0) {
                int tp = dir ? (TT - s) : (s - 1);
                hout[(size_t)tp * (2 * HH) + dir * HH + tid] = h;
            }
        }
        h_s[s & 1][tid] = h;
        xqC = xqN;
        if (s == TT) break;
        __syncthreads();                 // h(s) ready; dbuf covers the write side

        // dot: unit u's 4 gate rows x h_prev (4 ds_read_b128/thread)
        float a0 = 0.f, a1 = 0.f, a2 = 0.f, a3 = 0.f;
        const float4* h4 = (const float4*)h_s[s & 1];
        #pragma unroll
        for (int i = 0; i < 4; ++i) {
            float4 hv = h4[l + 32 * i];
            a0 += w[0  + i].x * hv.x + w[0  + i].y * hv.y + w[0  + i].z * hv.z + w[0  + i].w * hv.w;
            a1 += w[4  + i].x * hv.x + w[4  + i].y * hv.y + w[4  + i].z * hv.z + w[4  + i].w * hv.w;
            a2 += w[8  + i].x * hv.x + w[8  + i].y * hv.y + w[8  + i].z * hv.z + w[8  + i].w * hv.w;
            a3 += w[12 + i].x * hv.x + w[12 + i].y * hv.y + w[12 + i].z * hv.z + w[12 + i].w * hv.w;
        }
        #pragma unroll
        for (int m = 1; m <= 16; m <<= 1) {
            a0 += __shfl_xor(a0, m); a1 += __shfl_xor(a1, m);
            a2 += __shfl_xor(a2, m); a3 += __shfl_xor(a3, m);
        }
        if (l == 0) {
            u32x4 q; q.x = f2u(a0); q.y = f2u(a1); q.z = f2u(a2); q.w = f2u(a3);
            store16(gq + ((size_t)s * HH + u) * 4, q);
        }
    }
}

// ---------------- Viterbi forward + backtrack (bp in LDS, feats prefetch) ----
__global__ void viterbi_kernel(const float* __restrict__ feats,
                               const float* __restrict__ trans,
                               int* __restrict__ out) {
    const int n = threadIdx.x;   // blockDim = 64 (one wave)
    __shared__ float fv_s[NTAG];
    __shared__ uint8_t bp_s[TT][NTAG];   // 51200 B
    float tr[NTAG];
    if (n < NTAG) {
        #pragma unroll
        for (int p = 0; p < NTAG; ++p) tr[p] = trans[n * NTAG + p];
    }
    float fv = (n == 0) ? 0.f : NEGV;
    float fcur = (n < NTAG) ? feats[n] : 0.f;
    for (int t = 0; t < TT; ++t) {
        float fnext = (n < NTAG && t + 1 < TT) ? feats[(t + 1) * NTAG + n] : 0.f;
        if (n < NTAG) fv_s[n] = fv;
        __syncthreads();
        if (n < NTAG) {
            float best = -INFINITY; int bb = 0;
            #pragma unroll
            for (int p = 0; p < NTAG; ++p) {
                float sc = fv_s[p] + tr[p];
                if (sc > best) { best = sc; bb = p; }   // first-max tie rule
            }
            bp_s[t][n] = (uint8_t)bb;
            fv = best + fcur;
        }
        fcur = fnext;
        __syncthreads();
    }
    if (n < NTAG) fv_s[n] = fv;
    __syncthreads();
    if (n == 0) {
        float best = -INFINITY; int tag = 0;
        for (int p = 0; p < NTAG; ++p)
            if (fv_s[p] > best) { best = fv_s[p]; tag = p; }
        for (int t = TT - 1; t >= 0; --t) {
            out[t] = tag;
            tag = bp_s[t][tag];
        }
    }
}

extern "C" void kernel_launch(void* const* d_in, const int* in_sizes, int n_in,
                              void* d_out, int out_size, void* d_ws, size_t ws_size,
                              hipStream_t stream) {
    const int*   sent      = (const int*)d_in[0];
    const float* emb       = (const float*)d_in[1];
    const float* w_ih_l0_f = (const float*)d_in[2];
    const float* w_hh_l0_f = (const float*)d_in[3];
    const float* b_ih_l0_f = (const float*)d_in[4];
    const float* b_hh_l0_f = (const float*)d_in[5];
    const float* w_ih_l0_b = (const float*)d_in[6];
    const float* w_hh_l0_b = (const float*)d_in[7];
    const float* b_ih_l0_b = (const float*)d_in[8];
    const float* b_hh_l0_b = (const float*)d_in[9];
    const float* w_ih_l1_f = (const float*)d_in[10];
    const float* w_hh_l1_f = (const float*)d_in[11];
    const float* b_ih_l1_f = (const float*)d_in[12];
    const float* b_hh_l1_f = (const float*)d_in[13];
    const float* w_ih_l1_b = (const float*)d_in[14];
    const float* w_hh_l1_b = (const float*)d_in[15];
    const float* b_ih_l1_b = (const float*)d_in[16];
    const float* b_hh_l1_b = (const float*)d_in[17];
    const float* w_tag     = (const float*)d_in[18];
    const float* b_tag     = (const float*)d_in[19];
    const float* trans     = (const float*)d_in[20];

    char* ws = (char*)d_ws;
    float* x     = (float*)(ws);                 // T*300   = 2,457,600 B
    float* gx    = (float*)(ws + 2457600);       // 2*T*4H  = 33,554,432 B
    float* gates = (float*)(ws + 36012032);      // 2*T*4H  = 33,554,432 B ([2][T][512][4])
    float* h1    = (float*)(ws + 69566464);      // T*2H    = 8,388,608 B
    float* h2    = (float*)(ws + 77955072);      // T*2H    = 8,388,608 B
    float* feats = (float*)(ws + 86343680);      // T*25

    const int NGATES = 2 * TT * G4H;

    poison_kernel<<<2048, 256, 0, stream>>>((uint32_t*)gates, NGATES);

    embed_kernel<<<TT, 128, 0, stream>>>(sent, emb, x);

    dim3 g0(TT / BM, G4H / BN);
    gemm_abt<<<g0, 256, 0, stream>>>(x, EE, w_ih_l0_f, EE, b_ih_l0_f, b_hh_l0_f,
                                     gx, G4H, TT, G4H, EE);
    gemm_abt<<<g0, 256, 0, stream>>>(x, EE, w_ih_l0_b, EE, b_ih_l0_b, b_hh_l0_b,
                                     gx + (size_t)TT * G4H, G4H, TT, G4H, EE);
    lstm_kernel<<<64, 512, 0, stream>>>(gx, w_hh_l0_f, w_hh_l0_b, gates, h1);

    dim3 g1(TT / GM, G4H / GN);
    gemm128<<<g1, 256, 0, stream>>>(h1, 2 * HH, w_ih_l1_f, 2 * HH, b_ih_l1_f, b_hh_l1_f,
                                    gx, G4H, 2 * HH);
    gemm128<<<g1, 256, 0, stream>>>(h1, 2 * HH, w_ih_l1_b, 2 * HH, b_ih_l1_b, b_hh_l1_b,
                                    gx + (size_t)TT * G4H, G4H, 2 * HH);
    poison_kernel<<<2048, 256, 0, stream>>>((uint32_t*)gates, NGATES);
    lstm_kernel<<<64, 512, 0, stream>>>(gx, w_hh_l1_f, w_hh_l1_b, gates, h2);

    dim3 gf(TT / BM, 1);
    gemm_abt<<<gf, 256, 0, stream>>>(h2, 2 * HH, w_tag, 2 * HH, b_tag, nullptr,
                                     feats, NTAG, TT, NTAG, 2 * HH);

    viterbi_kernel<<<1, 64, 0, stream>>>(feats, trans, (int*)d_out);
}